// Round 2
// baseline (724.004 us; speedup 1.0000x reference)
//
#include <hip/hip_runtime.h>

// out[b,n,d] = sum_t vol[b,n,t] * M[d,t] + bias[d]
// M[d,t] = sum_{m<64} W[d][m]*cos(2pi m t/512) - W[d][64+m]*sin(2pi m t/512)
// GEMM: C (131072 x 512) = A (131072 x 512) * B^T (512 x 512) + bias
// Split-bf16 (hi/lo) x3 MFMA for fp32-grade accuracy.
// A staged in LDS (XOR-swizzled, double-buffered); B read from global (L2-hot).

typedef float f32x4 __attribute__((ext_vector_type(4)));
typedef short s16x8 __attribute__((ext_vector_type(8)));
typedef unsigned short u16;

__device__ __forceinline__ u16 f32_to_bf16_rne(float x) {
  unsigned u = __builtin_bit_cast(unsigned, x);
  unsigned r = 0x7FFFu + ((u >> 16) & 1u);
  return (u16)((u + r) >> 16);
}
__device__ __forceinline__ float bf16_to_f32(u16 h) {
  unsigned u = ((unsigned)h) << 16;
  return __builtin_bit_cast(float, u);
}

// ---------------- Kernel 1: build M = W * F, split into bf16 hi/lo ----------
// grid 512 (one block per d), block 256. Precise cosf table; sin via phase shift.
__global__ void build_M_kernel(const float* __restrict__ W,
                               u16* __restrict__ Mh, u16* __restrict__ Ml) {
  __shared__ float Wrow[128];
  __shared__ float tab[640];   // tab[i] = cos(2*pi*(i-128)/512); sin(r)=tab[r], cos(r)=tab[r+128]
  const int d = blockIdx.x;
  const int tid = threadIdx.x;
  if (tid < 128) Wrow[tid] = W[d * 128 + tid];
  for (int i = tid; i < 640; i += 256)
    tab[i] = cosf((float)(i - 128) * 0.012271846303085129f); // 2*pi/512
  __syncthreads();
#pragma unroll
  for (int tt = 0; tt < 2; ++tt) {
    const int t = tt * 256 + tid;
    float acc = 0.f;
#pragma unroll 8
    for (int m = 0; m < 64; ++m) {
      int r = (m * t) & 511;
      acc = fmaf(Wrow[m], tab[r + 128], acc);
      acc = fmaf(-Wrow[64 + m], tab[r], acc);
    }
    u16 h = f32_to_bf16_rne(acc);
    u16 l = f32_to_bf16_rne(acc - bf16_to_f32(h));
    Mh[d * 512 + t] = h;
    Ml[d * 512 + t] = l;
  }
}

// ---------------- Kernel 2: split-bf16 MFMA GEMM ----------------------------
// Tile BM=128, BN=128, BK=32, 16 K-steps. 256 threads = 4 waves (2x2 of 64x64).
// LDS: A only, [2 buf][h/l][128*32] u16 = 32 KB. B fragments from global regs.
__global__ __launch_bounds__(256, 3) void gemm_kernel(
    const float* __restrict__ A,   // vol: 131072 x 512 (f32)
    const u16* __restrict__ Bh,    // Mh:  512 x 512 (bf16 bits, d-major)
    const u16* __restrict__ Bl,    // Ml
    const float* __restrict__ bias,
    float* __restrict__ C) {       // 131072 x 512 (f32)
  __shared__ u16 ldsA[2][2][128 * 32];

  const int tid = threadIdx.x;
  const int lane = tid & 63;
  const int wid = tid >> 6;
  const int wm = wid >> 1;
  const int wn = wid & 1;
  const int rr = lane & 15;
  const int kg = lane >> 4;

  // XCD-aware swizzle: 4 col-blocks sharing an A-row-panel stay on one XCD.
  const int b = blockIdx.x;            // 4096 blocks, %8==0 -> bijective
  const int xcd = b & 7;
  const int s = b >> 3;
  const int row0 = (xcd * 128 + (s >> 2)) * 128;
  const int col0 = (s & 3) * 128;

  f32x4 acc[4][4];
#pragma unroll
  for (int m = 0; m < 4; ++m)
#pragma unroll
    for (int n = 0; n < 4; ++n)
      acc[m][n] = (f32x4){0.f, 0.f, 0.f, 0.f};

  // A staging: thread covers rows {i*32 + tid>>3}, 16B chunk c4 = tid&7
  const int ar = tid >> 3;
  const int ac4 = tid & 7;
  float4 areg[4];
  s16x8 bh[4], bl[4];

  auto loadA = [&](int ks) {
    const int k0 = ks * 32;
#pragma unroll
    for (int i = 0; i < 4; ++i)
      areg[i] = *(const float4*)(A + (size_t)(row0 + i * 32 + ar) * 512 + k0 + ac4 * 4);
  };

  auto writeA = [&](int buf) {
#pragma unroll
    for (int i = 0; i < 4; ++i) {
      const int r = i * 32 + ar;
      const int off = (r * 32 + ac4 * 4) ^ ((r & 7) << 3);  // XOR swizzle (16B granule)
      ushort4 hv, lv;
      u16 h;
      float x;
      x = areg[i].x; h = f32_to_bf16_rne(x); hv.x = h; lv.x = f32_to_bf16_rne(x - bf16_to_f32(h));
      x = areg[i].y; h = f32_to_bf16_rne(x); hv.y = h; lv.y = f32_to_bf16_rne(x - bf16_to_f32(h));
      x = areg[i].z; h = f32_to_bf16_rne(x); hv.z = h; lv.z = f32_to_bf16_rne(x - bf16_to_f32(h));
      x = areg[i].w; h = f32_to_bf16_rne(x); hv.w = h; lv.w = f32_to_bf16_rne(x - bf16_to_f32(h));
      *reinterpret_cast<ushort4*>(&ldsA[buf][0][off]) = hv;
      *reinterpret_cast<ushort4*>(&ldsA[buf][1][off]) = lv;
    }
  };

  auto loadB = [&](int ks) {
    const int k0 = ks * 32;
#pragma unroll
    for (int n = 0; n < 4; ++n) {
      const size_t off = (size_t)(col0 + wn * 64 + n * 16 + rr) * 512 + k0 + kg * 8;
      bh[n] = *(const s16x8*)(Bh + off);
      bl[n] = *(const s16x8*)(Bl + off);
    }
  };

  auto compute = [&](int buf) {
    s16x8 ah[4], al[4];
#pragma unroll
    for (int m = 0; m < 4; ++m) {
      const int r = wm * 64 + m * 16 + rr;
      const int off = (r * 32 + kg * 8) ^ ((r & 7) << 3);
      ah[m] = *(const s16x8*)&ldsA[buf][0][off];
      al[m] = *(const s16x8*)&ldsA[buf][1][off];
    }
#pragma unroll
    for (int m = 0; m < 4; ++m)
#pragma unroll
      for (int n = 0; n < 4; ++n) {
        acc[m][n] = __builtin_amdgcn_mfma_f32_16x16x32_bf16(ah[m], bh[n], acc[m][n], 0, 0, 0);
        acc[m][n] = __builtin_amdgcn_mfma_f32_16x16x32_bf16(al[m], bh[n], acc[m][n], 0, 0, 0);
        acc[m][n] = __builtin_amdgcn_mfma_f32_16x16x32_bf16(ah[m], bl[n], acc[m][n], 0, 0, 0);
      }
  };

  // prologue
  loadA(0);
  writeA(0);

  // main loop, unrolled x2 for static buf index (rule #20)
  for (int ks = 0; ks < 16; ks += 2) {
    __syncthreads();
    loadB(ks);                       // current-iter B (L2-hot, covered by ds_reads)
    loadA(ks + 1);                   // next-tile A issue-early (ks+1 <= 15 always)
    compute(0);
    writeA(1);                       // vmcnt(A) wait + cvt + swizzled ds_write
    __syncthreads();
    loadB(ks + 1);
    if (ks < 14) loadA(ks + 2);
    compute(1);
    if (ks < 14) writeA(0);
  }

  // epilogue: bias + store. C/D map: col = rr, row = kg*4 + reg j (m89-verified)
#pragma unroll
  for (int n = 0; n < 4; ++n) {
    const int ccol = col0 + wn * 64 + n * 16 + rr;
    const float bv = bias[ccol];
#pragma unroll
    for (int m = 0; m < 4; ++m) {
      const int r0 = row0 + wm * 64 + m * 16 + kg * 4;
#pragma unroll
      for (int j = 0; j < 4; ++j) {
        C[(size_t)(r0 + j) * 512 + ccol] = acc[m][n][j] + bv;
      }
    }
  }
}

extern "C" void kernel_launch(void* const* d_in, const int* in_sizes, int n_in,
                              void* d_out, int out_size, void* d_ws, size_t ws_size,
                              hipStream_t stream) {
  const float* vol = (const float*)d_in[0]; // 64*2048*512
  const float* W   = (const float*)d_in[1]; // 512*128
  const float* bia = (const float*)d_in[2]; // 512
  float* out = (float*)d_out;               // 64*2048*512

  u16* Mh = (u16*)d_ws;          // 512*512 bf16 hi
  u16* Ml = Mh + 512 * 512;      // 512*512 bf16 lo  (1 MB scratch)

  build_M_kernel<<<512, 256, 0, stream>>>(W, Mh, Ml);
  gemm_kernel<<<4096, 256, 0, stream>>>(vol, Mh, Ml, bia, out);
}